// Round 3
// baseline (122.343 us; speedup 1.0000x reference)
//
#include <hip/hip_runtime.h>

#define BATCH 8192
#define NF 1024
#define NS 50000
#define MOM 0.2f
#define ROWS 4   // rows per fused_bank block; 50000 % 4 == 0 -> 12500 blocks

// rowhead[y] = batch index of the FIRST occurrence of label y, or -1.
__global__ void init_rowhead(int* __restrict__ rowhead) {
    const int i = blockIdx.x * blockDim.x + threadIdx.x;
    if (i < NS) rowhead[i] = -1;
}

// For each batch index i: nxt[i] = smallest j>i with same label, else -1.
// If i is the first occurrence of its label, record rowhead[label] = i.
__global__ void build_chains(const int* __restrict__ labels,
                             int* __restrict__ rowhead, int* __restrict__ nxt) {
    const int i = blockIdx.x;
    const int y = labels[i];
    int earlier = 0;
    int nx = 0x7fffffff;
    for (int j = threadIdx.x; j < BATCH; j += blockDim.x) {
        if (j == i) continue;
        if (labels[j] == y) {
            if (j < i) earlier = 1;
            else nx = min(nx, j);
        }
    }
    for (int off = 32; off; off >>= 1) {
        earlier |= __shfl_xor(earlier, off, 64);
        nx = min(nx, __shfl_xor(nx, off, 64));
    }
    __shared__ int s_e[4], s_n[4];
    const int tid = threadIdx.x;
    if ((tid & 63) == 0) { s_e[tid >> 6] = earlier; s_n[tid >> 6] = nx; }
    __syncthreads();
    if (tid == 0) {
        const int e = s_e[0] | s_e[1] | s_e[2] | s_e[3];
        const int n = min(min(s_n[0], s_n[1]), min(s_n[2], s_n[3]));
        nxt[i] = (n == 0x7fffffff) ? -1 : n;
        if (!e) rowhead[y] = i;   // exactly one head per label -> no race
    }
}

// One block per 4 bank rows (256 threads x float4 per row = 64 B/lane in
// flight). Untouched rows: straight copy. Touched rows: walk the duplicate
// chain (block-uniform), momentum-blend + block-reduced L2 normalize each
// step, write once.
__global__ __launch_bounds__(256)
void fused_bank(const float* __restrict__ f_out,
                const float* __restrict__ features,
                const int* __restrict__ rowhead,
                const int* __restrict__ nxt,
                float* __restrict__ out) {
    const int y0 = blockIdx.x * ROWS;
    const int tid = threadIdx.x;

    float4 v[ROWS];
    #pragma unroll
    for (int k = 0; k < ROWS; ++k)
        v[k] = reinterpret_cast<const float4*>(features + (size_t)(y0 + k) * NF)[tid];

    int h[ROWS];
    #pragma unroll
    for (int k = 0; k < ROWS; ++k) h[k] = rowhead[y0 + k];  // block-uniform

    const int hm = max(max(h[0], h[1]), max(h[2], h[3]));
    if (hm >= 0) {   // at least one of the 4 rows is touched (block-uniform)
        __shared__ float s_part[4];
        const float m = MOM, om = 1.0f - MOM;
        #pragma unroll
        for (int k = 0; k < ROWS; ++k) {
            if (h[k] < 0) continue;          // block-uniform
            int j = h[k];
            while (j >= 0) {
                const float4 x =
                    reinterpret_cast<const float4*>(f_out + (size_t)j * NF)[tid];
                v[k].x = m * v[k].x + om * x.x;
                v[k].y = m * v[k].y + om * x.y;
                v[k].z = m * v[k].z + om * x.z;
                v[k].w = m * v[k].w + om * x.w;
                float s = v[k].x * v[k].x + v[k].y * v[k].y +
                          v[k].z * v[k].z + v[k].w * v[k].w;
                for (int off = 32; off; off >>= 1) s += __shfl_xor(s, off, 64);
                if ((tid & 63) == 0) s_part[tid >> 6] = s;
                __syncthreads();
                const float tot = s_part[0] + s_part[1] + s_part[2] + s_part[3];
                __syncthreads();  // protect s_part before next write
                const float inv = 1.0f / sqrtf(tot);
                v[k].x *= inv; v[k].y *= inv; v[k].z *= inv; v[k].w *= inv;
                j = nxt[j];
            }
        }
    }

    #pragma unroll
    for (int k = 0; k < ROWS; ++k)
        reinterpret_cast<float4*>(out + (size_t)(y0 + k) * NF)[tid] = v[k];
}

extern "C" void kernel_launch(void* const* d_in, const int* in_sizes, int n_in,
                              void* d_out, int out_size, void* d_ws, size_t ws_size,
                              hipStream_t stream) {
    const float* f_out    = (const float*)d_in[0];
    const float* features = (const float*)d_in[1];
    const int*   labels   = (const int*)d_in[2];
    float* out = (float*)d_out;

    int* rowhead = (int*)d_ws;          // NS ints
    int* nxt     = rowhead + NS;        // BATCH ints

    init_rowhead<<<(NS + 255) / 256, 256, 0, stream>>>(rowhead);
    build_chains<<<BATCH, 256, 0, stream>>>(labels, rowhead, nxt);
    fused_bank<<<NS / ROWS, 256, 0, stream>>>(f_out, features, rowhead, nxt, out);
}